// Round 11
// baseline (336.477 us; speedup 1.0000x reference)
//
#include <hip/hip_runtime.h>
#include <hip/hip_bf16.h>
#include <math.h>

#define BATCH   8192
#define IM      784
#define HDIM    3136
#define LAT     128
#define D2      392
#define B2      4096

// padded dims
#define IM_P    800     // K of GEMM1
#define HDIM_P  3200    // N of GEMM1 / K of GEMM2
#define N2_P    256     // mu||sigma combined
#define D2_P    512     // N of GEMM3 / K of GEMM4
#define IM_NP   896     // N of GEMM4 (logical 784)
#define KSPLIT  4
#define K2S     (HDIM_P / KSPLIT)   // 800
#define REC_BLOCKS ((IM_NP / 128) * (BATCH / 128))   // 448

typedef __attribute__((ext_vector_type(8))) short short8;
typedef __attribute__((ext_vector_type(4))) float f32x4;

__device__ __forceinline__ void async_load16(const __hip_bfloat16* g, __hip_bfloat16* l)
{
    __builtin_amdgcn_global_load_lds(
        (const __attribute__((address_space(1))) unsigned int*)g,
        (__attribute__((address_space(3))) unsigned int*)l,
        16, 0, 0);
}

// depth-2 counted wait: tiles t+1,t+2 may be in flight (2*L loads max).
// Leaving only the 2 youngest stages outstanding guarantees tile t landed.
// Per-wave count + following s_barrier => all waves' tile-t writes visible.
template <int L>
__device__ __forceinline__ void wait_tiles2(int rem)
{
    if (rem >= 2)      asm volatile("s_waitcnt vmcnt(%0)" :: "i"(2 * L) : "memory");
    else if (rem == 1) asm volatile("s_waitcnt vmcnt(%0)" :: "i"(L) : "memory");
    else               asm volatile("s_waitcnt vmcnt(0)" ::: "memory");
}
#define RAW_BARRIER() asm volatile("s_barrier" ::: "memory")

// ---------------------------------------------------------------------------
// prep mega-kernel: x fp32->bf16 pad (vectorized), all weight transposes,
// all bias pads — one launch.
// ---------------------------------------------------------------------------
#define PB_X    3200                 // 8192*100/256
#define PB_W11  (PB_X   + 2500)     // 25 x 100 tiles
#define PB_W3   (PB_W11 + 800)      // 2 x (100 x 4)
#define PB_W44  (PB_W3  + 64)       // 4 x 16
#define PB_W61  (PB_W44 + 448)      // 16 x 28
#define PB_END  (PB_W61 + 13)       // biases

__device__ __forceinline__ void transpose_tile(
    const float* __restrict__ in, __hip_bfloat16* __restrict__ out,
    int K, int N, int K_pad, int N_pad, int bx, int by, int tid)
{
    __shared__ float tile[32][33];
    int k0 = bx * 32, n0 = by * 32;
    int tx = tid & 31, ty = tid >> 5;
    #pragma unroll
    for (int j = 0; j < 4; ++j) {
        int k = k0 + ty + j * 8, n = n0 + tx;
        tile[ty + j * 8][tx] = (k < K && n < N) ? in[(size_t)k * N + n] : 0.f;
    }
    __syncthreads();
    #pragma unroll
    for (int j = 0; j < 4; ++j) {
        int n = n0 + ty + j * 8, k = k0 + tx;
        if (n < N_pad && k < K_pad)
            out[(size_t)n * K_pad + k] = __float2bfloat16(tile[tx][ty + j * 8]);
    }
}

__global__ __launch_bounds__(256)
void prep(const float* __restrict__ x,
          const float* __restrict__ W11, const float* __restrict__ W31,
          const float* __restrict__ W32, const float* __restrict__ W44,
          const float* __restrict__ W61,
          const float* __restrict__ b11, const float* __restrict__ b31,
          const float* __restrict__ b32, const float* __restrict__ b44,
          const float* __restrict__ b61,
          __hip_bfloat16* __restrict__ x_bf, __hip_bfloat16* __restrict__ W11T,
          __hip_bfloat16* __restrict__ W3xT, __hip_bfloat16* __restrict__ W44T,
          __hip_bfloat16* __restrict__ W61T,
          float* __restrict__ b11p, float* __restrict__ b3x,
          float* __restrict__ b44p, float* __restrict__ b61p)
{
    const int bid = blockIdx.x, tid = threadIdx.x;
    if (bid < PB_X) {
        int gid = bid * 256 + tid;       // 0..819199
        int m = gid / 100, ch = gid % 100;
        short8 v = {};
        if (ch < 98) {   // 784 = 98*8 exactly
            const float* src = x + (size_t)m * IM + ch * 8;
            float4 f0 = *reinterpret_cast<const float4*>(src);
            float4 f1 = *reinterpret_cast<const float4*>(src + 4);
            float f[8] = {f0.x, f0.y, f0.z, f0.w, f1.x, f1.y, f1.z, f1.w};
            #pragma unroll
            for (int k = 0; k < 8; ++k) {
                __hip_bfloat16 h = __float2bfloat16(f[k]);
                v[k] = *reinterpret_cast<short*>(&h);
            }
        }
        *reinterpret_cast<short8*>(&x_bf[(size_t)m * IM_P + ch * 8]) = v;
    } else if (bid < PB_W11) {
        int r = bid - PB_X;
        transpose_tile(W11, W11T, IM, HDIM, IM_P, HDIM_P, r % 25, r / 25, tid);
    } else if (bid < PB_W3) {
        int r = bid - PB_W11;
        int zz = r / 400; r %= 400;
        transpose_tile(zz ? W32 : W31, W3xT + (size_t)zz * 128 * HDIM_P,
                       HDIM, LAT, HDIM_P, 128, r % 100, r / 100, tid);
    } else if (bid < PB_W44) {
        int r = bid - PB_W3;
        transpose_tile(W44, W44T, LAT, D2, LAT, D2_P, r % 4, r / 4, tid);
    } else if (bid < PB_W61) {
        int r = bid - PB_W44;
        transpose_tile(W61, W61T, D2, IM, D2_P, IM_NP, r % 16, r / 16, tid);
    } else {
        int i = (bid - PB_W61) * 256 + tid;
        if (i < HDIM_P) b11p[i] = (i < HDIM) ? b11[i] : 0.f;
        if (i < LAT) { b3x[i] = b31[i]; b3x[LAT + i] = b32[i]; }
        if (i < D2_P) b44p[i] = (i < D2) ? b44[i] : 0.f;
        if (i < IM_NP) b61p[i] = (i < IM) ? b61[i] : 0.f;
    }
}

// ---------------------------------------------------------------------------
// MFMA GEMM, 128 x BN tile, 4 waves (2x2), BK=32, 16x16x32 bf16.
// 3-buffer LDS (48 KB -> 3 blocks/CU) + depth-2 counted-vmcnt prefetch:
// stage(t+2) issued at iter t; wait leaves the 2 youngest stages in flight
// (~2 iterations of latency cover) and retires tile-t. r4-r10 sweep:
// {16K,d0}=89, {32K,sync-d1}=85, {64K,d3}=96, {32K,d1}=84 us -> need cover
// AND occupancy together. Buffer safety: stage(t+2) targets buf[(t-1)%3],
// whose readers passed the end-of-iter-(t-1) barrier before this issues.
// Fragment-order LDS: staging writes and ds_read_b128 both stride-1,
// 0 bank conflicts (verified r4+).
// FUSE_REC: per-block rec-loss partial -> rec_arr[wg] (NO atomics, r7 lesson).
// ---------------------------------------------------------------------------
template <int BN, typename OutT, bool SIGMOID, bool FUSE_REC>
__global__ __launch_bounds__(256)
void gemm_mfma(const __hip_bfloat16* __restrict__ A, const __hip_bfloat16* __restrict__ BT,
               const float* __restrict__ bias, OutT* __restrict__ C,
               int K_pad, int N_logical, int ldc,
               const float* __restrict__ xin, double* __restrict__ rec_arr)
{
    constexpr int NI = BN / 32;
    constexpr int SL = (BN == 128) ? 4 : 3;   // loads per stage per wave
    __shared__ alignas(16) __hip_bfloat16 As[3][128 * 32];
    __shared__ alignas(16) __hip_bfloat16 Bs[3][BN * 32];
    __shared__ float shr[4];

    const int t    = threadIdx.x;
    const int wave = t >> 6;
    const int lane = t & 63;
    const int wr   = wave >> 1;
    const int wc   = wave & 1;

    // XCD-aware swizzle (all grids are multiples of 8)
    const int nwg = gridDim.x * gridDim.y;
    const int wg  = blockIdx.y * gridDim.x + blockIdx.x;
    const int swz = (wg & 7) * (nwg >> 3) + (wg >> 3);
    const int m0  = (swz / gridDim.x) * 128;
    const int n0  = (swz % gridDim.x) * BN;

    const int srow = lane & 15;
    const int skc  = lane >> 4;
    const __hip_bfloat16* Ag = A + (size_t)(m0 + wave * 32 + srow) * K_pad + skc * 8;
    const __hip_bfloat16* Bg;
    if constexpr (BN == 128)
        Bg = BT + (size_t)(n0 + wave * 32 + srow) * K_pad + skc * 8;
    else
        Bg = BT + (size_t)(n0 + wave * 16 + srow) * K_pad + skc * 8;

    auto stage = [&](int buf, int kt) {
        async_load16(Ag + kt, &As[buf][(wave * 2 + 0) * 512]);
        async_load16(Ag + (size_t)16 * K_pad + kt, &As[buf][(wave * 2 + 1) * 512]);
        if constexpr (BN == 128) {
            async_load16(Bg + kt, &Bs[buf][(wave * 2 + 0) * 512]);
            async_load16(Bg + (size_t)16 * K_pad + kt, &Bs[buf][(wave * 2 + 1) * 512]);
        } else {
            async_load16(Bg + kt, &Bs[buf][wave * 512]);
        }
    };

    f32x4 acc[4][NI] = {};
    const int nt = K_pad >> 5;

    stage(0, 0);
    if (nt > 1) stage(1, 32);

    int cur = 0;
    for (int tt = 0; tt < nt; ++tt) {
        int stg = cur + 2; if (stg >= 3) stg -= 3;
        if (tt + 2 < nt) stage(stg, (tt + 2) << 5);
        wait_tiles2<SL>(nt - 1 - tt);
        __builtin_amdgcn_sched_barrier(0);
        RAW_BARRIER();                 // tile tt visible in LDS for all waves

        short8 af[4], bfv[NI];
        #pragma unroll
        for (int mi = 0; mi < 4; ++mi)
            af[mi] = *reinterpret_cast<const short8*>(&As[cur][(wr * 4 + mi) * 512 + lane * 8]);
        #pragma unroll
        for (int ni = 0; ni < NI; ++ni)
            bfv[ni] = *reinterpret_cast<const short8*>(&Bs[cur][(wc * NI + ni) * 512 + lane * 8]);

        #pragma unroll
        for (int mi = 0; mi < 4; ++mi)
            #pragma unroll
            for (int ni = 0; ni < NI; ++ni)
                acc[mi][ni] = __builtin_amdgcn_mfma_f32_16x16x32_bf16(
                    af[mi], bfv[ni], acc[mi][ni], 0, 0, 0);

        RAW_BARRIER();                 // all reads of buf[cur] done
        cur = (cur + 1 == 3) ? 0 : cur + 1;
    }

    // epilogue: C/D layout col = lane&15, row = (lane>>4)*4 + reg
    const int fr   = lane & 15;
    const int row4 = (lane >> 4) * 4;
    float rsum = 0.f;
    #pragma unroll
    for (int ni = 0; ni < NI; ++ni) {
        int gn = n0 + wc * (BN / 2) + ni * 16 + fr;
        if (gn >= N_logical) continue;
        float bv = bias[gn];
        #pragma unroll
        for (int mi = 0; mi < 4; ++mi) {
            #pragma unroll
            for (int r = 0; r < 4; ++r) {
                int gm = m0 + wr * 64 + mi * 16 + row4 + r;
                float o = acc[mi][ni][r] + bv;
                o = fmaxf(o, 0.f);
                if (SIGMOID) o = 1.f / (1.f + expf(-o));
                if constexpr (sizeof(OutT) == 2)
                    C[(size_t)gm * ldc + gn] = __float2bfloat16(o);
                else
                    C[(size_t)gm * ldc + gn] = o;
                if constexpr (FUSE_REC) {
                    float xv = xin[(size_t)gm * ldc + gn];
                    float l1 = fmaxf(__logf(o), -100.f);
                    float l2 = fmaxf(__logf(1.f - o), -100.f);
                    rsum += xv * l1 + (1.f - xv) * l2;
                }
            }
        }
    }
    if constexpr (FUSE_REC) {
        for (int off = 32; off; off >>= 1) rsum += __shfl_down(rsum, off);
        if (lane == 0) shr[wave] = rsum;
        __syncthreads();
        if (t == 0)
            rec_arr[wg] = (double)(-(shr[0] + shr[1] + shr[2] + shr[3]));
    }
}

// ---------------------------------------------------------------------------
// split-K GEMM2 (BN=64, raw partials), 3-buffer depth-2 counted pipeline.
// LDS = 36 KB -> 4 blocks/CU.
// ---------------------------------------------------------------------------
__global__ __launch_bounds__(256)
void gemm_mfma_splitk(const __hip_bfloat16* __restrict__ A, const __hip_bfloat16* __restrict__ BT,
                      float* __restrict__ partial, int K_pad)
{
    constexpr int BN = 64, NI = 2, SL = 3;
    __shared__ alignas(16) __hip_bfloat16 As[3][128 * 32];
    __shared__ alignas(16) __hip_bfloat16 Bs[3][BN * 32];

    const int t    = threadIdx.x;
    const int wave = t >> 6;
    const int lane = t & 63;
    const int wr   = wave >> 1;
    const int wc   = wave & 1;

    const int nwg = gridDim.x * gridDim.y;
    const int wg  = blockIdx.y * gridDim.x + blockIdx.x;
    const int swz = (wg & 7) * (nwg >> 3) + (wg >> 3);
    const int m0  = (swz / gridDim.x) * 128;
    const int n0  = (swz % gridDim.x) * BN;
    const int koff = blockIdx.z * K2S;

    const int srow = lane & 15;
    const int skc  = lane >> 4;
    const __hip_bfloat16* Ag = A + (size_t)(m0 + wave * 32 + srow) * K_pad + skc * 8 + koff;
    const __hip_bfloat16* Bg = BT + (size_t)(n0 + wave * 16 + srow) * K_pad + skc * 8 + koff;

    auto stage = [&](int buf, int kt) {
        async_load16(Ag + kt, &As[buf][(wave * 2 + 0) * 512]);
        async_load16(Ag + (size_t)16 * K_pad + kt, &As[buf][(wave * 2 + 1) * 512]);
        async_load16(Bg + kt, &Bs[buf][wave * 512]);
    };

    f32x4 acc[4][NI] = {};
    const int nt = K2S >> 5;   // 25

    stage(0, 0);
    stage(1, 32);

    int cur = 0;
    for (int tt = 0; tt < nt; ++tt) {
        int stg = cur + 2; if (stg >= 3) stg -= 3;
        if (tt + 2 < nt) stage(stg, (tt + 2) << 5);
        wait_tiles2<SL>(nt - 1 - tt);
        __builtin_amdgcn_sched_barrier(0);
        RAW_BARRIER();

        short8 af[4], bfv[NI];
        #pragma unroll
        for (int mi = 0; mi < 4; ++mi)
            af[mi] = *reinterpret_cast<const short8*>(&As[cur][(wr * 4 + mi) * 512 + lane * 8]);
        #pragma unroll
        for (int ni = 0; ni < NI; ++ni)
            bfv[ni] = *reinterpret_cast<const short8*>(&Bs[cur][(wc * NI + ni) * 512 + lane * 8]);

        #pragma unroll
        for (int mi = 0; mi < 4; ++mi)
            #pragma unroll
            for (int ni = 0; ni < NI; ++ni)
                acc[mi][ni] = __builtin_amdgcn_mfma_f32_16x16x32_bf16(
                    af[mi], bfv[ni], acc[mi][ni], 0, 0, 0);

        RAW_BARRIER();
        cur = (cur + 1 == 3) ? 0 : cur + 1;
    }

    const int fr   = lane & 15;
    const int row4 = (lane >> 4) * 4;
    float* out = partial + (size_t)blockIdx.z * BATCH * 256;
    #pragma unroll
    for (int ni = 0; ni < NI; ++ni) {
        int gn = n0 + wc * 32 + ni * 16 + fr;
        #pragma unroll
        for (int mi = 0; mi < 4; ++mi) {
            #pragma unroll
            for (int r = 0; r < 4; ++r) {
                int gm = m0 + wr * 64 + mi * 16 + row4 + r;
                out[(size_t)gm * 256 + gn] = acc[mi][ni][r];
            }
        }
    }
}

// ---------------------------------------------------------------------------
// reduce split-K partials + bias + relu; z = eps*sig + mu; per-pair stats.
// NO atomics: dkl/a/c stored per-block, reduced by moments_kernel.
// ---------------------------------------------------------------------------
__global__ __launch_bounds__(128)
void reduce_stats(const float* __restrict__ partial, const float* __restrict__ b3x,
                  const float* __restrict__ eps, __hip_bfloat16* __restrict__ z,
                  float* __restrict__ a_out, float* __restrict__ c_out,
                  float* __restrict__ dkl_out)
{
    const int b = blockIdx.x;       // pair 0..4095
    const int j = threadIdx.x;      // latent 0..127
    const size_t r1 = (size_t)b * 256;
    const size_t r2 = (size_t)(B2 + b) * 256;

    float mu1 = 0.f, sg1 = 0.f, mu2 = 0.f, sg2 = 0.f;
    #pragma unroll
    for (int s = 0; s < KSPLIT; ++s) {
        const float* p = partial + (size_t)s * BATCH * 256;
        mu1 += p[r1 + j];  sg1 += p[r1 + 128 + j];
        mu2 += p[r2 + j];  sg2 += p[r2 + 128 + j];
    }
    const float bm = b3x[j], bs = b3x[128 + j];
    mu1 = fmaxf(mu1 + bm, 0.f); sg1 = fmaxf(sg1 + bs, 0.f);
    mu2 = fmaxf(mu2 + bm, 0.f); sg2 = fmaxf(sg2 + bs, 0.f);
    z[(size_t)b * LAT + j]        = __float2bfloat16(fmaf(eps[(size_t)b * LAT + j], sg1, mu1));
    z[(size_t)(B2 + b) * LAT + j] = __float2bfloat16(fmaf(eps[(size_t)(B2 + b) * LAT + j], sg2, mu2));

    float s1 = sg1 + 1e-8f, s2 = sg2 + 1e-8f;
    float sm = 0.5f * (s1 + s2), mm = 0.5f * (mu1 + mu2);
    float dkl = -1.f - logf(1e-8f + sm * sm) + mm * mm + sm * sm;
    float tr  = s1 / s2;
    float df  = mu2 - mu1;
    float dq  = df * df / s2;
    float p1  = s1, p2 = s2;

    for (int off = 32; off; off >>= 1) {
        dkl += __shfl_down(dkl, off);
        tr  += __shfl_down(tr, off);
        dq  += __shfl_down(dq, off);
        p1  *= __shfl_down(p1, off);
        p2  *= __shfl_down(p2, off);
    }
    __shared__ float sh[5][2];
    const int wid = j >> 6;
    if ((j & 63) == 0) { sh[0][wid] = dkl; sh[1][wid] = tr; sh[2][wid] = dq;
                         sh[3][wid] = p1;  sh[4][wid] = p2; }
    __syncthreads();
    if (j == 0) {
        dkl = sh[0][0] + sh[0][1];
        tr  = sh[1][0] + sh[1][1];
        dq  = sh[2][0] + sh[2][1];
        p1  = sh[3][0] * sh[3][1];
        p2  = sh[4][0] * sh[4][1];
        float e = logf(1e-8f + p2 / (p1 + 1e-8f)) - (float)LAT;
        a_out[b]   = 0.5f * dq;
        c_out[b]   = 0.5f * (tr + e);
        dkl_out[b] = 0.5f * dkl;
    }
}

// ---------------------------------------------------------------------------
// one-block moments: Sigma dkl -> accs[1]; S1=-Sigma a; S2 from P1,P2,Q.
// ---------------------------------------------------------------------------
__global__ __launch_bounds__(1024)
void moments_kernel(const float* __restrict__ a, const float* __restrict__ c,
                    const float* __restrict__ dkl, double* __restrict__ accs)
{
    __shared__ double sh[4][16];
    const int tid = threadIdx.x, wid = tid >> 6, lane = tid & 63;
    double sd = 0.0, p1 = 0.0, p2 = 0.0, q = 0.0;
    #pragma unroll
    for (int k = 0; k < 4; ++k) {
        int i = tid + k * 1024;
        double av = a[i], cv = c[i];
        sd += dkl[i];
        p1 += cv;
        p2 += av;
        double d = cv - av;
        q  += d * d;
    }
    for (int off = 32; off; off >>= 1) {
        sd += __shfl_down(sd, off);
        p1 += __shfl_down(p1, off);
        p2 += __shfl_down(p2, off);
        q  += __shfl_down(q, off);
    }
    if (lane == 0) { sh[0][wid] = sd; sh[1][wid] = p1; sh[2][wid] = p2; sh[3][wid] = q; }
    __syncthreads();
    if (tid == 0) {
        double SD = 0, P1 = 0, P2 = 0, Q = 0;
        for (int w = 0; w < 16; ++w) { SD += sh[0][w]; P1 += sh[1][w]; P2 += sh[2][w]; Q += sh[3][w]; }
        double cbar = P1 / (double)B2;
        accs[1] = SD;
        accs[4] = -P2;                                              // S1
        accs[5] = Q - 2.0 * cbar * (P1 - P2) + (double)B2 * cbar * cbar;  // S2
    }
}

// ---------------------------------------------------------------------------
// l_diverse row scan + l_smooth row value; NO atomics (per-row arrays).
// c[] is 16 KB -> L1-resident; read directly (no LDS staging), float4.
// ---------------------------------------------------------------------------
__global__ __launch_bounds__(256)
void ldiv_smooth(const float* __restrict__ a, const float* __restrict__ c,
                 const double* __restrict__ accs,
                 float* __restrict__ ld_out, double* __restrict__ sm_out)
{
    __shared__ float sh[4];
    int i = blockIdx.x;
    float ai = a[i];
    float part = 0.f;
    const float4* c4 = reinterpret_cast<const float4*>(c);
    for (int j4 = threadIdx.x; j4 < B2 / 4; j4 += 256) {
        float4 cc = c4[j4];
        float cv[4] = {cc.x, cc.y, cc.z, cc.w};
        #pragma unroll
        for (int u = 0; u < 4; ++u) {
            float tv = -(ai + cv[u]);
            float r = (tv > 0.f) ? (tv + log1pf(__expf(-tv))) : log1pf(__expf(tv));
            part += r;
        }
    }
    for (int off = 32; off; off >>= 1) part += __shfl_down(part, off);
    int wid = threadIdx.x >> 6;
    if ((threadIdx.x & 63) == 0) sh[wid] = part;
    __syncthreads();
    if (threadIdx.x == 0) {
        ld_out[i] = sh[0] + sh[1] + sh[2] + sh[3];
        double S1 = accs[4], S2 = accs[5];
        double aa = (double)ai;
        double q = ((double)B2 * aa * aa + 2.0 * aa * S1 + S2) / (double)(LAT - 1);
        sm_out[i] = sqrt(fmax(q, 0.0));
    }
}

// ---------------------------------------------------------------------------
// final: loss = Sigma rec_arr + accs[1] + Sigma ld + Sigma sm
// ---------------------------------------------------------------------------
__global__ __launch_bounds__(1024)
void final_kernel(const double* __restrict__ rec_arr, const float* __restrict__ ld,
                  const double* __restrict__ sm, const double* __restrict__ accs,
                  float* __restrict__ out_loss)
{
    __shared__ double sh[16];
    const int tid = threadIdx.x, wid = tid >> 6, lane = tid & 63;
    double s = 0.0;
    if (tid < REC_BLOCKS) s += rec_arr[tid];
    #pragma unroll
    for (int k = 0; k < 4; ++k) {
        int i = tid + k * 1024;
        s += (double)ld[i] + sm[i];
    }
    for (int off = 32; off; off >>= 1) s += __shfl_down(s, off);
    if (lane == 0) sh[wid] = s;
    __syncthreads();
    if (tid == 0) {
        double tot = accs[1];
        for (int w = 0; w < 16; ++w) tot += sh[w];
        out_loss[0] = (float)tot;
    }
}

extern "C" void kernel_launch(void* const* d_in, const int* in_sizes, int n_in,
                              void* d_out, int out_size, void* d_ws, size_t ws_size,
                              hipStream_t stream)
{
    const float* x   = (const float*)d_in[0];
    const float* eps = (const float*)d_in[1];
    const float* W11 = (const float*)d_in[2];
    const float* b11 = (const float*)d_in[3];
    const float* W31 = (const float*)d_in[4];
    const float* b31 = (const float*)d_in[5];
    const float* W32 = (const float*)d_in[6];
    const float* b32 = (const float*)d_in[7];
    const float* W44 = (const float*)d_in[8];
    const float* b44 = (const float*)d_in[9];
    const float* W61 = (const float*)d_in[10];
    const float* b61 = (const float*)d_in[11];
    float* out = (float*)d_out;

    char* ws = (char*)d_ws;
    size_t off = 0;
    auto alloc = [&](size_t bytes) {
        void* p = ws + off;
        off += (bytes + 255) & ~(size_t)255;
        return p;
    };
    __hip_bfloat16* x_bf    = (__hip_bfloat16*)alloc((size_t)BATCH * IM_P * 2);
    __hip_bfloat16* W11T    = (__hip_bfloat16*)alloc((size_t)HDIM_P * IM_P * 2);
    float*          b11p    = (float*)alloc(HDIM_P * 4);
    __hip_bfloat16* enc     = (__hip_bfloat16*)alloc((size_t)BATCH * HDIM_P * 2);
    __hip_bfloat16* W3xT    = (__hip_bfloat16*)alloc((size_t)N2_P * HDIM_P * 2);
    float*          b3x     = (float*)alloc(N2_P * 4);
    __hip_bfloat16* z_bf    = (__hip_bfloat16*)alloc((size_t)BATCH * LAT * 2);
    __hip_bfloat16* W44T    = (__hip_bfloat16*)alloc((size_t)D2_P * LAT * 2);
    float*          b44p    = (float*)alloc(D2_P * 4);
    __hip_bfloat16* dec     = (__hip_bfloat16*)alloc((size_t)BATCH * D2_P * 2);
    __hip_bfloat16* W61T    = (__hip_bfloat16*)alloc((size_t)IM_NP * D2_P * 2);
    float*          b61p    = (float*)alloc(IM_NP * 4);
    float*          av      = (float*)alloc(B2 * 4);
    float*          cv      = (float*)alloc(B2 * 4);
    float*          dklv    = (float*)alloc(B2 * 4);
    float*          ldv     = (float*)alloc(B2 * 4);
    double*         smv     = (double*)alloc(B2 * 8);
    double*         rec_arr = (double*)alloc(REC_BLOCKS * 8);
    double*         accs    = (double*)alloc(8 * sizeof(double));
    float*          partial = (float*)alloc((size_t)KSPLIT * BATCH * N2_P * 4);

    hipMemsetAsync(accs, 0, 8 * sizeof(double), stream);

    // one preprocessing launch
    prep<<<PB_END, 256, 0, stream>>>(x, W11, W31, W32, W44, W61,
                                     b11, b31, b32, b44, b61,
                                     x_bf, W11T, W3xT, W44T, W61T,
                                     b11p, b3x, b44p, b61p);

    // enc = relu(x @ W11 + b11)  [8192 x 3200]
    gemm_mfma<128, __hip_bfloat16, false, false>
        <<<dim3(HDIM_P / 128, BATCH / 128), 256, 0, stream>>>(
        x_bf, W11T, b11p, enc, IM_P, HDIM_P, HDIM_P, nullptr, nullptr);
    // musig partials = enc @ [W31|W32]  (split-K, 1024 blocks)
    gemm_mfma_splitk<<<dim3(N2_P / 64, BATCH / 128, KSPLIT), 256, 0, stream>>>(
        enc, W3xT, partial, HDIM_P);
    // reduce + bias + relu + z + per-pair stats (no atomics)
    reduce_stats<<<B2, 128, 0, stream>>>(partial, b3x, eps, z_bf, av, cv, dklv);
    // one-block moment reduction
    moments_kernel<<<1, 1024, 0, stream>>>(av, cv, dklv, accs);
    // dec = relu(z @ W44 + b44)  [8192 x 512]
    gemm_mfma<128, __hip_bfloat16, false, false>
        <<<dim3(D2_P / 128, BATCH / 128), 256, 0, stream>>>(
        z_bf, W44T, b44p, dec, LAT, D2_P, D2_P, nullptr, nullptr);
    // y = sigmoid(relu(dec @ W61 + b61)) -> d_out, rec-loss partials fused
    gemm_mfma<128, float, true, true>
        <<<dim3(IM_NP / 128, BATCH / 128), 256, 0, stream>>>(
        dec, W61T, b61p, out, D2_P, IM, IM, x, rec_arr);
    // diverse + smooth per-row (no atomics)
    ldiv_smooth<<<B2, 256, 0, stream>>>(av, cv, accs, ldv, smv);
    // final loss
    final_kernel<<<1, 1024, 0, stream>>>(rec_arr, ldv, smv, accs, out + (size_t)BATCH * IM);
}

// Round 12
// 316.959 us; speedup vs baseline: 1.0616x; 1.0616x over previous
//
#include <hip/hip_runtime.h>
#include <hip/hip_bf16.h>
#include <math.h>

#define BATCH   8192
#define IM      784
#define HDIM    3136
#define LAT     128
#define D2      392
#define B2      4096

// padded dims
#define IM_P    800     // K of GEMM1
#define HDIM_P  3200    // N of GEMM1 / K of GEMM2
#define N2_P    256     // mu||sigma combined
#define D2_P    512     // N of GEMM3 / K of GEMM4
#define IM_NP   896     // N of GEMM4 (logical 784)
#define KSPLIT  4
#define K2S     (HDIM_P / KSPLIT)   // 800
#define REC_BLOCKS ((IM_NP / 128) * (BATCH / 128))   // 448

typedef __attribute__((ext_vector_type(8))) short short8;
typedef __attribute__((ext_vector_type(4))) float f32x4;

__device__ __forceinline__ void async_load16(const __hip_bfloat16* g, __hip_bfloat16* l)
{
    __builtin_amdgcn_global_load_lds(
        (const __attribute__((address_space(1))) unsigned int*)g,
        (__attribute__((address_space(3))) unsigned int*)l,
        16, 0, 0);
}

// depth-1 counted wait: leave tile-(t+1)'s L loads outstanding, retire tile-t.
template <int L>
__device__ __forceinline__ void wait_prev(int rem)
{
    if (rem >= 1) asm volatile("s_waitcnt vmcnt(%0)" :: "i"(L) : "memory");
    else          asm volatile("s_waitcnt vmcnt(0)" ::: "memory");
}
// depth-2 counted wait (3-buffer kernels)
template <int L>
__device__ __forceinline__ void wait_tiles2(int rem)
{
    if (rem >= 2)      asm volatile("s_waitcnt vmcnt(%0)" :: "i"(2 * L) : "memory");
    else if (rem == 1) asm volatile("s_waitcnt vmcnt(%0)" :: "i"(L) : "memory");
    else               asm volatile("s_waitcnt vmcnt(0)" ::: "memory");
}
#define RAW_BARRIER() asm volatile("s_barrier" ::: "memory")

// ---------------------------------------------------------------------------
// prep mega-kernel
// ---------------------------------------------------------------------------
#define PB_X    3200                 // 8192*100/256
#define PB_W11  (PB_X   + 2500)     // 25 x 100 tiles
#define PB_W3   (PB_W11 + 800)      // 2 x (100 x 4)
#define PB_W44  (PB_W3  + 64)      // 4 x 16
#define PB_W61  (PB_W44 + 448)     // 16 x 28
#define PB_END  (PB_W61 + 13)      // biases

__device__ __forceinline__ void transpose_tile(
    const float* __restrict__ in, __hip_bfloat16* __restrict__ out,
    int K, int N, int K_pad, int N_pad, int bx, int by, int tid)
{
    __shared__ float tile[32][33];
    int k0 = bx * 32, n0 = by * 32;
    int tx = tid & 31, ty = tid >> 5;
    #pragma unroll
    for (int j = 0; j < 4; ++j) {
        int k = k0 + ty + j * 8, n = n0 + tx;
        tile[ty + j * 8][tx] = (k < K && n < N) ? in[(size_t)k * N + n] : 0.f;
    }
    __syncthreads();
    #pragma unroll
    for (int j = 0; j < 4; ++j) {
        int n = n0 + ty + j * 8, k = k0 + tx;
        if (n < N_pad && k < K_pad)
            out[(size_t)n * K_pad + k] = __float2bfloat16(tile[tx][ty + j * 8]);
    }
}

__global__ __launch_bounds__(256)
void prep(const float* __restrict__ x,
          const float* __restrict__ W11, const float* __restrict__ W31,
          const float* __restrict__ W32, const float* __restrict__ W44,
          const float* __restrict__ W61,
          const float* __restrict__ b11, const float* __restrict__ b31,
          const float* __restrict__ b32, const float* __restrict__ b44,
          const float* __restrict__ b61,
          __hip_bfloat16* __restrict__ x_bf, __hip_bfloat16* __restrict__ W11T,
          __hip_bfloat16* __restrict__ W3xT, __hip_bfloat16* __restrict__ W44T,
          __hip_bfloat16* __restrict__ W61T,
          float* __restrict__ b11p, float* __restrict__ b3x,
          float* __restrict__ b44p, float* __restrict__ b61p)
{
    const int bid = blockIdx.x, tid = threadIdx.x;
    if (bid < PB_X) {
        int gid = bid * 256 + tid;       // 0..819199
        int m = gid / 100, ch = gid % 100;
        short8 v = {};
        if (ch < 98) {   // 784 = 98*8 exactly
            const float* src = x + (size_t)m * IM + ch * 8;
            float4 f0 = *reinterpret_cast<const float4*>(src);
            float4 f1 = *reinterpret_cast<const float4*>(src + 4);
            float f[8] = {f0.x, f0.y, f0.z, f0.w, f1.x, f1.y, f1.z, f1.w};
            #pragma unroll
            for (int k = 0; k < 8; ++k) {
                __hip_bfloat16 h = __float2bfloat16(f[k]);
                v[k] = *reinterpret_cast<short*>(&h);
            }
        }
        *reinterpret_cast<short8*>(&x_bf[(size_t)m * IM_P + ch * 8]) = v;
    } else if (bid < PB_W11) {
        int r = bid - PB_X;
        transpose_tile(W11, W11T, IM, HDIM, IM_P, HDIM_P, r % 25, r / 25, tid);
    } else if (bid < PB_W3) {
        int r = bid - PB_W11;
        int zz = r / 400; r %= 400;
        transpose_tile(zz ? W32 : W31, W3xT + (size_t)zz * 128 * HDIM_P,
                       HDIM, LAT, HDIM_P, 128, r % 100, r / 100, tid);
    } else if (bid < PB_W44) {
        int r = bid - PB_W3;
        transpose_tile(W44, W44T, LAT, D2, LAT, D2_P, r % 4, r / 4, tid);
    } else if (bid < PB_W61) {
        int r = bid - PB_W44;
        transpose_tile(W61, W61T, D2, IM, D2_P, IM_NP, r % 16, r / 16, tid);
    } else {
        int i = (bid - PB_W61) * 256 + tid;
        if (i < HDIM_P) b11p[i] = (i < HDIM) ? b11[i] : 0.f;
        if (i < LAT) { b3x[i] = b31[i]; b3x[LAT + i] = b32[i]; }
        if (i < D2_P) b44p[i] = (i < D2) ? b44[i] : 0.f;
        if (i < IM_NP) b61p[i] = (i < IM) ? b61[i] : 0.f;
    }
}

// ---------------------------------------------------------------------------
// GEMM1: 8-wave (512thr) 256x128 tile, BK=32, 2-buffer (48KB) depth-1
// counted prefetch. Per-wave resources identical to the 4-wave kernel
// (4x4 frags, ~80 VGPR) but waves/CU 12 -> 24 (3 blocks x 8 waves):
// r4-r11 sweep showed depth is saturated and occupancy is the binding
// constraint. Fragment-order LDS, 0 bank conflicts.
// Wave w stages A chunks 2w,2w+1 (rows 32w..32w+31) + B chunk w (cols 16w..).
// ---------------------------------------------------------------------------
__global__ __launch_bounds__(512)
void gemm_mfma_8w(const __hip_bfloat16* __restrict__ A, const __hip_bfloat16* __restrict__ BT,
                  const float* __restrict__ bias, __hip_bfloat16* __restrict__ C,
                  int K_pad, int N_dim)
{
    __shared__ alignas(16) __hip_bfloat16 As[2][256 * 32];
    __shared__ alignas(16) __hip_bfloat16 Bs[2][128 * 32];

    const int t    = threadIdx.x;
    const int wave = t >> 6;          // 0..7
    const int lane = t & 63;
    const int wr   = wave >> 1;       // 0..3
    const int wc   = wave & 1;        // 0..1

    const int nwg = gridDim.x * gridDim.y;   // 800, %8==0
    const int wg  = blockIdx.y * gridDim.x + blockIdx.x;
    const int swz = (wg & 7) * (nwg >> 3) + (wg >> 3);
    const int m0  = (swz / gridDim.x) * 256;
    const int n0  = (swz % gridDim.x) * 128;

    const int srow = lane & 15;
    const int skc  = lane >> 4;
    const __hip_bfloat16* Ag = A + (size_t)(m0 + wave * 32 + srow) * K_pad + skc * 8;
    const __hip_bfloat16* Bg = BT + (size_t)(n0 + wave * 16 + srow) * K_pad + skc * 8;

    auto stage = [&](int buf, int kt) {
        async_load16(Ag + kt, &As[buf][(wave * 2 + 0) * 512]);
        async_load16(Ag + (size_t)16 * K_pad + kt, &As[buf][(wave * 2 + 1) * 512]);
        async_load16(Bg + kt, &Bs[buf][wave * 512]);
    };

    f32x4 acc[4][4] = {};
    const int nt = K_pad >> 5;   // 25

    stage(0, 0);

    for (int tt = 0; tt < nt; ++tt) {
        if (tt + 1 < nt) stage((tt + 1) & 1, (tt + 1) << 5);
        wait_prev<3>(nt - 1 - tt);
        __builtin_amdgcn_sched_barrier(0);
        RAW_BARRIER();

        const int cur = tt & 1;
        short8 af[4], bfv[4];
        #pragma unroll
        for (int mi = 0; mi < 4; ++mi)
            af[mi] = *reinterpret_cast<const short8*>(&As[cur][(wr * 4 + mi) * 512 + lane * 8]);
        #pragma unroll
        for (int ni = 0; ni < 4; ++ni)
            bfv[ni] = *reinterpret_cast<const short8*>(&Bs[cur][(wc * 4 + ni) * 512 + lane * 8]);

        #pragma unroll
        for (int mi = 0; mi < 4; ++mi)
            #pragma unroll
            for (int ni = 0; ni < 4; ++ni)
                acc[mi][ni] = __builtin_amdgcn_mfma_f32_16x16x32_bf16(
                    af[mi], bfv[ni], acc[mi][ni], 0, 0, 0);

        RAW_BARRIER();
    }

    const int fr   = lane & 15;
    const int row4 = (lane >> 4) * 4;
    #pragma unroll
    for (int ni = 0; ni < 4; ++ni) {
        int gn = n0 + wc * 64 + ni * 16 + fr;
        float bv = bias[gn];
        #pragma unroll
        for (int mi = 0; mi < 4; ++mi) {
            #pragma unroll
            for (int r = 0; r < 4; ++r) {
                int gm = m0 + wr * 64 + mi * 16 + row4 + r;
                float o = fmaxf(acc[mi][ni][r] + bv, 0.f);
                C[(size_t)gm * N_dim + gn] = __float2bfloat16(o);
            }
        }
    }
}

// ---------------------------------------------------------------------------
// MFMA GEMM (GEMM3/GEMM4), 128 x BN tile, 4 waves, 3-buffer depth-2.
// ---------------------------------------------------------------------------
template <int BN, typename OutT, bool SIGMOID, bool FUSE_REC>
__global__ __launch_bounds__(256)
void gemm_mfma(const __hip_bfloat16* __restrict__ A, const __hip_bfloat16* __restrict__ BT,
               const float* __restrict__ bias, OutT* __restrict__ C,
               int K_pad, int N_logical, int ldc,
               const float* __restrict__ xin, double* __restrict__ rec_arr)
{
    constexpr int NI = BN / 32;
    constexpr int SL = (BN == 128) ? 4 : 3;
    __shared__ alignas(16) __hip_bfloat16 As[3][128 * 32];
    __shared__ alignas(16) __hip_bfloat16 Bs[3][BN * 32];
    __shared__ float shr[4];

    const int t    = threadIdx.x;
    const int wave = t >> 6;
    const int lane = t & 63;
    const int wr   = wave >> 1;
    const int wc   = wave & 1;

    const int nwg = gridDim.x * gridDim.y;
    const int wg  = blockIdx.y * gridDim.x + blockIdx.x;
    const int swz = (wg & 7) * (nwg >> 3) + (wg >> 3);
    const int m0  = (swz / gridDim.x) * 128;
    const int n0  = (swz % gridDim.x) * BN;

    const int srow = lane & 15;
    const int skc  = lane >> 4;
    const __hip_bfloat16* Ag = A + (size_t)(m0 + wave * 32 + srow) * K_pad + skc * 8;
    const __hip_bfloat16* Bg;
    if constexpr (BN == 128)
        Bg = BT + (size_t)(n0 + wave * 32 + srow) * K_pad + skc * 8;
    else
        Bg = BT + (size_t)(n0 + wave * 16 + srow) * K_pad + skc * 8;

    auto stage = [&](int buf, int kt) {
        async_load16(Ag + kt, &As[buf][(wave * 2 + 0) * 512]);
        async_load16(Ag + (size_t)16 * K_pad + kt, &As[buf][(wave * 2 + 1) * 512]);
        if constexpr (BN == 128) {
            async_load16(Bg + kt, &Bs[buf][(wave * 2 + 0) * 512]);
            async_load16(Bg + (size_t)16 * K_pad + kt, &Bs[buf][(wave * 2 + 1) * 512]);
        } else {
            async_load16(Bg + kt, &Bs[buf][wave * 512]);
        }
    };

    f32x4 acc[4][NI] = {};
    const int nt = K_pad >> 5;

    stage(0, 0);
    if (nt > 1) stage(1, 32);

    int cur = 0;
    for (int tt = 0; tt < nt; ++tt) {
        int stg = cur + 2; if (stg >= 3) stg -= 3;
        if (tt + 2 < nt) stage(stg, (tt + 2) << 5);
        wait_tiles2<SL>(nt - 1 - tt);
        __builtin_amdgcn_sched_barrier(0);
        RAW_BARRIER();

        short8 af[4], bfv[NI];
        #pragma unroll
        for (int mi = 0; mi < 4; ++mi)
            af[mi] = *reinterpret_cast<const short8*>(&As[cur][(wr * 4 + mi) * 512 + lane * 8]);
        #pragma unroll
        for (int ni = 0; ni < NI; ++ni)
            bfv[ni] = *reinterpret_cast<const short8*>(&Bs[cur][(wc * NI + ni) * 512 + lane * 8]);

        #pragma unroll
        for (int mi = 0; mi < 4; ++mi)
            #pragma unroll
            for (int ni = 0; ni < NI; ++ni)
                acc[mi][ni] = __builtin_amdgcn_mfma_f32_16x16x32_bf16(
                    af[mi], bfv[ni], acc[mi][ni], 0, 0, 0);

        RAW_BARRIER();
        cur = (cur + 1 == 3) ? 0 : cur + 1;
    }

    const int fr   = lane & 15;
    const int row4 = (lane >> 4) * 4;
    float rsum = 0.f;
    #pragma unroll
    for (int ni = 0; ni < NI; ++ni) {
        int gn = n0 + wc * (BN / 2) + ni * 16 + fr;
        if (gn >= N_logical) continue;
        float bv = bias[gn];
        #pragma unroll
        for (int mi = 0; mi < 4; ++mi) {
            #pragma unroll
            for (int r = 0; r < 4; ++r) {
                int gm = m0 + wr * 64 + mi * 16 + row4 + r;
                float o = acc[mi][ni][r] + bv;
                o = fmaxf(o, 0.f);
                if (SIGMOID) o = 1.f / (1.f + expf(-o));
                if constexpr (sizeof(OutT) == 2)
                    C[(size_t)gm * ldc + gn] = __float2bfloat16(o);
                else
                    C[(size_t)gm * ldc + gn] = o;
                if constexpr (FUSE_REC) {
                    float xv = xin[(size_t)gm * ldc + gn];
                    float l1 = fmaxf(__logf(o), -100.f);
                    float l2 = fmaxf(__logf(1.f - o), -100.f);
                    rsum += xv * l1 + (1.f - xv) * l2;
                }
            }
        }
    }
    if constexpr (FUSE_REC) {
        for (int off = 32; off; off >>= 1) rsum += __shfl_down(rsum, off);
        if (lane == 0) shr[wave] = rsum;
        __syncthreads();
        if (t == 0)
            rec_arr[wg] = (double)(-(shr[0] + shr[1] + shr[2] + shr[3]));
    }
}

// ---------------------------------------------------------------------------
// split-K GEMM2 (BN=64, raw partials), 3-buffer depth-2 counted pipeline.
// ---------------------------------------------------------------------------
__global__ __launch_bounds__(256)
void gemm_mfma_splitk(const __hip_bfloat16* __restrict__ A, const __hip_bfloat16* __restrict__ BT,
                      float* __restrict__ partial, int K_pad)
{
    constexpr int BN = 64, NI = 2, SL = 3;
    __shared__ alignas(16) __hip_bfloat16 As[3][128 * 32];
    __shared__ alignas(16) __hip_bfloat16 Bs[3][BN * 32];

    const int t    = threadIdx.x;
    const int wave = t >> 6;
    const int lane = t & 63;
    const int wr   = wave >> 1;
    const int wc   = wave & 1;

    const int nwg = gridDim.x * gridDim.y;
    const int wg  = blockIdx.y * gridDim.x + blockIdx.x;
    const int swz = (wg & 7) * (nwg >> 3) + (wg >> 3);
    const int m0  = (swz / gridDim.x) * 128;
    const int n0  = (swz % gridDim.x) * BN;
    const int koff = blockIdx.z * K2S;

    const int srow = lane & 15;
    const int skc  = lane >> 4;
    const __hip_bfloat16* Ag = A + (size_t)(m0 + wave * 32 + srow) * K_pad + skc * 8 + koff;
    const __hip_bfloat16* Bg = BT + (size_t)(n0 + wave * 16 + srow) * K_pad + skc * 8 + koff;

    auto stage = [&](int buf, int kt) {
        async_load16(Ag + kt, &As[buf][(wave * 2 + 0) * 512]);
        async_load16(Ag + (size_t)16 * K_pad + kt, &As[buf][(wave * 2 + 1) * 512]);
        async_load16(Bg + kt, &Bs[buf][wave * 512]);
    };

    f32x4 acc[4][NI] = {};
    const int nt = K2S >> 5;   // 25

    stage(0, 0);
    stage(1, 32);

    int cur = 0;
    for (int tt = 0; tt < nt; ++tt) {
        int stg = cur + 2; if (stg >= 3) stg -= 3;
        if (tt + 2 < nt) stage(stg, (tt + 2) << 5);
        wait_tiles2<SL>(nt - 1 - tt);
        __builtin_amdgcn_sched_barrier(0);
        RAW_BARRIER();

        short8 af[4], bfv[NI];
        #pragma unroll
        for (int mi = 0; mi < 4; ++mi)
            af[mi] = *reinterpret_cast<const short8*>(&As[cur][(wr * 4 + mi) * 512 + lane * 8]);
        #pragma unroll
        for (int ni = 0; ni < NI; ++ni)
            bfv[ni] = *reinterpret_cast<const short8*>(&Bs[cur][(wc * NI + ni) * 512 + lane * 8]);

        #pragma unroll
        for (int mi = 0; mi < 4; ++mi)
            #pragma unroll
            for (int ni = 0; ni < NI; ++ni)
                acc[mi][ni] = __builtin_amdgcn_mfma_f32_16x16x32_bf16(
                    af[mi], bfv[ni], acc[mi][ni], 0, 0, 0);

        RAW_BARRIER();
        cur = (cur + 1 == 3) ? 0 : cur + 1;
    }

    const int fr   = lane & 15;
    const int row4 = (lane >> 4) * 4;
    float* out = partial + (size_t)blockIdx.z * BATCH * 256;
    #pragma unroll
    for (int ni = 0; ni < NI; ++ni) {
        int gn = n0 + wc * 32 + ni * 16 + fr;
        #pragma unroll
        for (int mi = 0; mi < 4; ++mi) {
            #pragma unroll
            for (int r = 0; r < 4; ++r) {
                int gm = m0 + wr * 64 + mi * 16 + row4 + r;
                out[(size_t)gm * 256 + gn] = acc[mi][ni][r];
            }
        }
    }
}

// ---------------------------------------------------------------------------
// reduce split-K partials + bias + relu; z; per-pair stats. NO atomics.
// ---------------------------------------------------------------------------
__global__ __launch_bounds__(128)
void reduce_stats(const float* __restrict__ partial, const float* __restrict__ b3x,
                  const float* __restrict__ eps, __hip_bfloat16* __restrict__ z,
                  float* __restrict__ a_out, float* __restrict__ c_out,
                  float* __restrict__ dkl_out)
{
    const int b = blockIdx.x;
    const int j = threadIdx.x;
    const size_t r1 = (size_t)b * 256;
    const size_t r2 = (size_t)(B2 + b) * 256;

    float mu1 = 0.f, sg1 = 0.f, mu2 = 0.f, sg2 = 0.f;
    #pragma unroll
    for (int s = 0; s < KSPLIT; ++s) {
        const float* p = partial + (size_t)s * BATCH * 256;
        mu1 += p[r1 + j];  sg1 += p[r1 + 128 + j];
        mu2 += p[r2 + j];  sg2 += p[r2 + 128 + j];
    }
    const float bm = b3x[j], bs = b3x[128 + j];
    mu1 = fmaxf(mu1 + bm, 0.f); sg1 = fmaxf(sg1 + bs, 0.f);
    mu2 = fmaxf(mu2 + bm, 0.f); sg2 = fmaxf(sg2 + bs, 0.f);
    z[(size_t)b * LAT + j]        = __float2bfloat16(fmaf(eps[(size_t)b * LAT + j], sg1, mu1));
    z[(size_t)(B2 + b) * LAT + j] = __float2bfloat16(fmaf(eps[(size_t)(B2 + b) * LAT + j], sg2, mu2));

    float s1 = sg1 + 1e-8f, s2 = sg2 + 1e-8f;
    float sm = 0.5f * (s1 + s2), mm = 0.5f * (mu1 + mu2);
    float dkl = -1.f - logf(1e-8f + sm * sm) + mm * mm + sm * sm;
    float tr  = s1 / s2;
    float df  = mu2 - mu1;
    float dq  = df * df / s2;
    float p1  = s1, p2 = s2;

    for (int off = 32; off; off >>= 1) {
        dkl += __shfl_down(dkl, off);
        tr  += __shfl_down(tr, off);
        dq  += __shfl_down(dq, off);
        p1  *= __shfl_down(p1, off);
        p2  *= __shfl_down(p2, off);
    }
    __shared__ float sh[5][2];
    const int wid = j >> 6;
    if ((j & 63) == 0) { sh[0][wid] = dkl; sh[1][wid] = tr; sh[2][wid] = dq;
                         sh[3][wid] = p1;  sh[4][wid] = p2; }
    __syncthreads();
    if (j == 0) {
        dkl = sh[0][0] + sh[0][1];
        tr  = sh[1][0] + sh[1][1];
        dq  = sh[2][0] + sh[2][1];
        p1  = sh[3][0] * sh[3][1];
        p2  = sh[4][0] * sh[4][1];
        float e = logf(1e-8f + p2 / (p1 + 1e-8f)) - (float)LAT;
        a_out[b]   = 0.5f * dq;
        c_out[b]   = 0.5f * (tr + e);
        dkl_out[b] = 0.5f * dkl;
    }
}

__global__ __launch_bounds__(1024)
void moments_kernel(const float* __restrict__ a, const float* __restrict__ c,
                    const float* __restrict__ dkl, double* __restrict__ accs)
{
    __shared__ double sh[4][16];
    const int tid = threadIdx.x, wid = tid >> 6, lane = tid & 63;
    double sd = 0.0, p1 = 0.0, p2 = 0.0, q = 0.0;
    #pragma unroll
    for (int k = 0; k < 4; ++k) {
        int i = tid + k * 1024;
        double av = a[i], cv = c[i];
        sd += dkl[i];
        p1 += cv;
        p2 += av;
        double d = cv - av;
        q  += d * d;
    }
    for (int off = 32; off; off >>= 1) {
        sd += __shfl_down(sd, off);
        p1 += __shfl_down(p1, off);
        p2 += __shfl_down(p2, off);
        q  += __shfl_down(q, off);
    }
    if (lane == 0) { sh[0][wid] = sd; sh[1][wid] = p1; sh[2][wid] = p2; sh[3][wid] = q; }
    __syncthreads();
    if (tid == 0) {
        double SD = 0, P1 = 0, P2 = 0, Q = 0;
        for (int w = 0; w < 16; ++w) { SD += sh[0][w]; P1 += sh[1][w]; P2 += sh[2][w]; Q += sh[3][w]; }
        double cbar = P1 / (double)B2;
        accs[1] = SD;
        accs[4] = -P2;                                              // S1
        accs[5] = Q - 2.0 * cbar * (P1 - P2) + (double)B2 * cbar * cbar;  // S2
    }
}

__global__ __launch_bounds__(256)
void ldiv_smooth(const float* __restrict__ a, const float* __restrict__ c,
                 const double* __restrict__ accs,
                 float* __restrict__ ld_out, double* __restrict__ sm_out)
{
    __shared__ float sh[4];
    int i = blockIdx.x;
    float ai = a[i];
    float part = 0.f;
    const float4* c4 = reinterpret_cast<const float4*>(c);
    for (int j4 = threadIdx.x; j4 < B2 / 4; j4 += 256) {
        float4 cc = c4[j4];
        float cv[4] = {cc.x, cc.y, cc.z, cc.w};
        #pragma unroll
        for (int u = 0; u < 4; ++u) {
            float tv = -(ai + cv[u]);
            float r = (tv > 0.f) ? (tv + log1pf(__expf(-tv))) : log1pf(__expf(tv));
            part += r;
        }
    }
    for (int off = 32; off; off >>= 1) part += __shfl_down(part, off);
    int wid = threadIdx.x >> 6;
    if ((threadIdx.x & 63) == 0) sh[wid] = part;
    __syncthreads();
    if (threadIdx.x == 0) {
        ld_out[i] = sh[0] + sh[1] + sh[2] + sh[3];
        double S1 = accs[4], S2 = accs[5];
        double aa = (double)ai;
        double q = ((double)B2 * aa * aa + 2.0 * aa * S1 + S2) / (double)(LAT - 1);
        sm_out[i] = sqrt(fmax(q, 0.0));
    }
}

__global__ __launch_bounds__(1024)
void final_kernel(const double* __restrict__ rec_arr, const float* __restrict__ ld,
                  const double* __restrict__ sm, const double* __restrict__ accs,
                  float* __restrict__ out_loss)
{
    __shared__ double sh[16];
    const int tid = threadIdx.x, wid = tid >> 6, lane = tid & 63;
    double s = 0.0;
    if (tid < REC_BLOCKS) s += rec_arr[tid];
    #pragma unroll
    for (int k = 0; k < 4; ++k) {
        int i = tid + k * 1024;
        s += (double)ld[i] + sm[i];
    }
    for (int off = 32; off; off >>= 1) s += __shfl_down(s, off);
    if (lane == 0) sh[wid] = s;
    __syncthreads();
    if (tid == 0) {
        double tot = accs[1];
        for (int w = 0; w < 16; ++w) tot += sh[w];
        out_loss[0] = (float)tot;
    }
}

extern "C" void kernel_launch(void* const* d_in, const int* in_sizes, int n_in,
                              void* d_out, int out_size, void* d_ws, size_t ws_size,
                              hipStream_t stream)
{
    const float* x   = (const float*)d_in[0];
    const float* eps = (const float*)d_in[1];
    const float* W11 = (const float*)d_in[2];
    const float* b11 = (const float*)d_in[3];
    const float* W31 = (const float*)d_in[4];
    const float* b31 = (const float*)d_in[5];
    const float* W32 = (const float*)d_in[6];
    const float* b32 = (const float*)d_in[7];
    const float* W44 = (const float*)d_in[8];
    const float* b44 = (const float*)d_in[9];
    const float* W61 = (const float*)d_in[10];
    const float* b61 = (const float*)d_in[11];
    float* out = (float*)d_out;

    char* ws = (char*)d_ws;
    size_t off = 0;
    auto alloc = [&](size_t bytes) {
        void* p = ws + off;
        off += (bytes + 255) & ~(size_t)255;
        return p;
    };
    __hip_bfloat16* x_bf    = (__hip_bfloat16*)alloc((size_t)BATCH * IM_P * 2);
    __hip_bfloat16* W11T    = (__hip_bfloat16*)alloc((size_t)HDIM_P * IM_P * 2);
    float*          b11p    = (float*)alloc(HDIM_P * 4);
    __hip_bfloat16* enc     = (__hip_bfloat16*)alloc((size_t)BATCH * HDIM_P * 2);
    __hip_bfloat16* W3xT    = (__hip_bfloat16*)alloc((size_t)N2_P * HDIM_P * 2);
    float*          b3x     = (float*)alloc(N2_P * 4);
    __hip_bfloat16* z_bf    = (__hip_bfloat16*)alloc((size_t)BATCH * LAT * 2);
    __hip_bfloat16* W44T    = (__hip_bfloat16*)alloc((size_t)D2_P * LAT * 2);
    float*          b44p    = (float*)alloc(D2_P * 4);
    __hip_bfloat16* dec     = (__hip_bfloat16*)alloc((size_t)BATCH * D2_P * 2);
    __hip_bfloat16* W61T    = (__hip_bfloat16*)alloc((size_t)IM_NP * D2_P * 2);
    float*          b61p    = (float*)alloc(IM_NP * 4);
    float*          av      = (float*)alloc(B2 * 4);
    float*          cv      = (float*)alloc(B2 * 4);
    float*          dklv    = (float*)alloc(B2 * 4);
    float*          ldv     = (float*)alloc(B2 * 4);
    double*         smv     = (double*)alloc(B2 * 8);
    double*         rec_arr = (double*)alloc(REC_BLOCKS * 8);
    double*         accs    = (double*)alloc(8 * sizeof(double));
    float*          partial = (float*)alloc((size_t)KSPLIT * BATCH * N2_P * 4);

    hipMemsetAsync(accs, 0, 8 * sizeof(double), stream);

    // one preprocessing launch
    prep<<<PB_END, 256, 0, stream>>>(x, W11, W31, W32, W44, W61,
                                     b11, b31, b32, b44, b61,
                                     x_bf, W11T, W3xT, W44T, W61T,
                                     b11p, b3x, b44p, b61p);

    // enc = relu(x @ W11 + b11)  [8192 x 3200]  (8-wave 256x128, 800 blocks)
    gemm_mfma_8w<<<dim3(HDIM_P / 128, BATCH / 256), 512, 0, stream>>>(
        x_bf, W11T, b11p, enc, IM_P, HDIM_P);
    // musig partials = enc @ [W31|W32]  (split-K, 1024 blocks)
    gemm_mfma_splitk<<<dim3(N2_P / 64, BATCH / 128, KSPLIT), 256, 0, stream>>>(
        enc, W3xT, partial, HDIM_P);
    // reduce + bias + relu + z + per-pair stats (no atomics)
    reduce_stats<<<B2, 128, 0, stream>>>(partial, b3x, eps, z_bf, av, cv, dklv);
    // one-block moment reduction
    moments_kernel<<<1, 1024, 0, stream>>>(av, cv, dklv, accs);
    // dec = relu(z @ W44 + b44)  [8192 x 512]
    gemm_mfma<128, __hip_bfloat16, false, false>
        <<<dim3(D2_P / 128, BATCH / 128), 256, 0, stream>>>(
        z_bf, W44T, b44p, dec, LAT, D2_P, D2_P, nullptr, nullptr);
    // y = sigmoid(relu(dec @ W61 + b61)) -> d_out, rec-loss partials fused
    gemm_mfma<128, float, true, true>
        <<<dim3(IM_NP / 128, BATCH / 128), 256, 0, stream>>>(
        dec, W61T, b61p, out, D2_P, IM, IM, x, rec_arr);
    // diverse + smooth per-row (no atomics)
    ldiv_smooth<<<B2, 256, 0, stream>>>(av, cv, accs, ldv, smv);
    // final loss
    final_kernel<<<1, 1024, 0, stream>>>(rec_arr, ldv, smv, accs, out + (size_t)BATCH * IM);
}